// Round 1
// 278.508 us; speedup vs baseline: 1.2090x; 1.2090x over previous
//
#include <hip/hip_runtime.h>
#include <hip/hip_bf16.h>

// q = x@Wq^T*scale; k = y@Wk^T; v = y@Wv^T
// out = strict_lower(q@k^T) @ v  -- computed as causal LINEAR attention:
//   out_t = q_t @ P_t + strict_tril(q_t k_t^T) @ v_t,  P_t = sum_{c<t} k_c^T v_c
// Chunks of 128 rows (= tile). H_c = k_c^T v_c stored TRANSPOSED (Ht[c][n][d])
// so prefix is elementwise and the inter B-operand is K-contiguous.
//
// v6: replaces s_gemm (2080 blocks, 68MiB S buffer) + pv_gemm (atomics,
// latency-bound at 20% MfmaUtil) with h_gemm + prefix_scan + out_gemm.
// Attention FLOPs 68.8 GF -> ~11 GF. No atomics, no memset.
// All GEMMs: m97 structure (global_load_lds w=16, XOR-swizzled source chunks).
// ws (bf16 elems): q[4M] k[4M] v[4M](->kT) vT[4M] | xb[16M](->Ht) yb[16M](->Pt)
//   wq/wk/wv[1M x3]. Peak ~107 MiB, same as v5.

typedef __bf16 bf16x8 __attribute__((ext_vector_type(8)));
typedef __bf16 bf16x4 __attribute__((ext_vector_type(4)));
typedef float f32x4 __attribute__((ext_vector_type(4)));

#define MFMA16(a, b, c) __builtin_amdgcn_mfma_f32_16x16x32_bf16(a, b, c, 0, 0, 0)

constexpr float SCALE = 0.04419417382415922f; // 1/sqrt(512)

__device__ __forceinline__ void ld16(const void* g, void* l) {
    __builtin_amdgcn_global_load_lds(
        (__attribute__((address_space(1))) void*)g,
        (__attribute__((address_space(3))) void*)l, 16, 0, 0);
}

// read data-chunk c (16B) of row r from a [128][64] bf16 tile stored with
// slot = c ^ (r&7) swizzle. base = &S[0][0].
__device__ __forceinline__ bf16x8 frag(const __bf16* base, int r, int c) {
    return *(const bf16x8*)((const char*)base + r * 128 + ((c ^ (r & 7)) * 16));
}

__device__ inline bf16x8 pack8(float4 a, float4 b) {
    bf16x8 r;
    r[0] = (__bf16)a.x; r[1] = (__bf16)a.y; r[2] = (__bf16)a.z; r[3] = (__bf16)a.w;
    r[4] = (__bf16)b.x; r[5] = (__bf16)b.y; r[6] = (__bf16)b.z; r[7] = (__bf16)b.w;
    return r;
}

// ---------------------------------------------------------------------------
// fp32 -> bf16 conversion, one launch. unit = 8 floats.
// ---------------------------------------------------------------------------
__global__ __launch_bounds__(256) void convert_all(
    const float* __restrict__ x, const float* __restrict__ y,
    const float* __restrict__ wqf, const float* __restrict__ wkf,
    const float* __restrict__ wvf, __bf16* __restrict__ xb,
    __bf16* __restrict__ yb, __bf16* __restrict__ wqb,
    __bf16* __restrict__ wkb, __bf16* __restrict__ wvb)
{
    size_t uid = (size_t)blockIdx.x * 256 + threadIdx.x;
    const float* src; __bf16* dst; size_t off;
    if (uid < 2097152)      { src = x;   dst = xb;  off = uid; }
    else if (uid < 4194304) { src = y;   dst = yb;  off = uid - 2097152; }
    else if (uid < 4325376) { src = wqf; dst = wqb; off = uid - 4194304; }
    else if (uid < 4456448) { src = wkf; dst = wkb; off = uid - 4325376; }
    else                    { src = wvf; dst = wvb; off = uid - 4456448; }
    float4 a = ((const float4*)src)[off * 2];
    float4 b = ((const float4*)src)[off * 2 + 1];
    *(bf16x8*)(dst + off * 8) = pack8(a, b);
}

// ---------------------------------------------------------------------------
// bf16 GEMM: C[8192,512] = A[8192,2048] @ B[512,2048]^T  (z selects q/k/v).
// z==0 (q) folds SCALE into the epilogue.
// ---------------------------------------------------------------------------
__global__ __launch_bounds__(256, 3) void gemm_qkv_bf16(
    const __bf16* __restrict__ xb, const __bf16* __restrict__ yb,
    const __bf16* __restrict__ wq, const __bf16* __restrict__ wk,
    const __bf16* __restrict__ wv, __bf16* __restrict__ qo,
    __bf16* __restrict__ ko, __bf16* __restrict__ vo)
{
    constexpr int K = 2048, N = 512;
    __shared__ __align__(16) __bf16 As[128][64];
    __shared__ __align__(16) __bf16 Bs[128][64];

    const int z = blockIdx.z;
    const __bf16* A = (z == 0) ? xb : yb;
    const __bf16* B = (z == 0) ? wq : (z == 1) ? wk : wv;
    __bf16* C = (z == 0) ? qo : (z == 1) ? ko : vo;
    const float mul = (z == 0) ? SCALE : 1.0f;

    const int tid  = threadIdx.x;
    const int wave = tid >> 6, lane = tid & 63;
    const int fr = lane & 15, fq = lane >> 4;
    const int m0 = blockIdx.x * 128, n0 = blockIdx.y * 128;
    const int wr = (wave >> 1) * 64, wc = (wave & 1) * 64;
    const int lr = lane >> 3;
    const int cd = (lane & 7) ^ lr;

    f32x4 acc[4][4];
#pragma unroll
    for (int a = 0; a < 4; ++a)
#pragma unroll
        for (int b = 0; b < 4; ++b) acc[a][b] = f32x4{0.f, 0.f, 0.f, 0.f};

    const __bf16* ag = A + (size_t)(m0 + wave * 32 + lr) * K + cd * 8;
    const __bf16* bg = B + (size_t)(n0 + wave * 32 + lr) * K + cd * 8;
    __bf16* al = &As[wave * 32][0];
    __bf16* bl = &Bs[wave * 32][0];

    for (int kk = 0; kk < K; kk += 64) {
        __syncthreads();
#pragma unroll
        for (int u = 0; u < 4; ++u) {
            ld16(ag + (size_t)(u * 8) * K + kk, al + u * 512);
            ld16(bg + (size_t)(u * 8) * K + kk, bl + u * 512);
        }
        __syncthreads();
#pragma unroll
        for (int ks = 0; ks < 2; ++ks) {
            bf16x8 af[4], bf[4];
#pragma unroll
            for (int rt = 0; rt < 4; ++rt)
                af[rt] = frag(&As[0][0], wr + rt * 16 + fr, ks * 4 + fq);
#pragma unroll
            for (int nt = 0; nt < 4; ++nt)
                bf[nt] = frag(&Bs[0][0], wc + nt * 16 + fr, ks * 4 + fq);
#pragma unroll
            for (int rt = 0; rt < 4; ++rt)
#pragma unroll
                for (int nt = 0; nt < 4; ++nt)
                    acc[rt][nt] = MFMA16(af[rt], bf[nt], acc[rt][nt]);
        }
    }

#pragma unroll
    for (int rt = 0; rt < 4; ++rt)
#pragma unroll
        for (int nt = 0; nt < 4; ++nt) {
            const int col = n0 + wc + nt * 16 + fr;
#pragma unroll
            for (int r = 0; r < 4; ++r) {
                const int row = m0 + wr + rt * 16 + fq * 4 + r;
                C[(size_t)row * N + col] = (__bf16)(acc[rt][nt][r] * mul);
            }
        }
}

// ---------------------------------------------------------------------------
// Transpose [8192,512] -> [512,8192] (bf16), 64x64 LDS tiles. Used for v, k.
// ---------------------------------------------------------------------------
__global__ __launch_bounds__(256) void transpose_v(
    const ushort* __restrict__ v, ushort* __restrict__ vT)
{
    __shared__ ushort tile[64][72];
    const int t = threadIdx.x;
    const int r0 = blockIdx.x * 64;
    const int c0 = blockIdx.y * 64;
    const int lr = t >> 2;
    const int lc = (t & 3) * 16;

    union { float4 f[2]; ushort s[16]; } u;
    const float4* vp = (const float4*)(v + (size_t)(r0 + lr) * 512 + c0 + lc);
    u.f[0] = vp[0];
    u.f[1] = vp[1];
#pragma unroll
    for (int e = 0; e < 16; ++e) tile[lc + e][lr] = u.s[e];
    __syncthreads();
    float4* op = (float4*)(vT + (size_t)(c0 + lr) * 8192 + r0 + lc);
    op[0] = *(const float4*)&tile[lr][lc];
    op[1] = *(const float4*)&tile[lr][lc + 8];
}

// ---------------------------------------------------------------------------
// H kernel: Ht[c][n][d] = sum_{r in chunk c} v[cB+r][n] * k[cB+r][d]
// = (vT_c @ kT_c^T), chunk B=128 rows. grid (16 tiles, 63 chunks), K=128.
// ---------------------------------------------------------------------------
__global__ __launch_bounds__(256, 3) void h_gemm(
    const __bf16* __restrict__ vT, const __bf16* __restrict__ kT,
    __bf16* __restrict__ Ht)
{
    __shared__ __align__(16) __bf16 As[128][64];
    __shared__ __align__(16) __bf16 Bs[128][64];

    const int c  = blockIdx.y;              // chunk 0..62 (Ht[63] never read)
    const int m0 = (blockIdx.x & 3) * 128;  // n (v feature)
    const int n0 = (blockIdx.x >> 2) * 128; // d (k feature)

    const int tid  = threadIdx.x;
    const int wave = tid >> 6, lane = tid & 63;
    const int fr = lane & 15, fq = lane >> 4;
    const int wr = (wave >> 1) * 64, wc = (wave & 1) * 64;
    const int lr = lane >> 3;
    const int cd = (lane & 7) ^ lr;

    f32x4 acc[4][4];
#pragma unroll
    for (int a = 0; a < 4; ++a)
#pragma unroll
        for (int b = 0; b < 4; ++b) acc[a][b] = f32x4{0.f, 0.f, 0.f, 0.f};

    const __bf16* ag = vT + (size_t)(m0 + wave * 32 + lr) * 8192 + c * 128 + cd * 8;
    const __bf16* bg = kT + (size_t)(n0 + wave * 32 + lr) * 8192 + c * 128 + cd * 8;
    __bf16* al = &As[wave * 32][0];
    __bf16* bl = &Bs[wave * 32][0];

    for (int kk = 0; kk < 128; kk += 64) {
        __syncthreads();
#pragma unroll
        for (int u = 0; u < 4; ++u) {
            ld16(ag + (size_t)(u * 8) * 8192 + kk, al + u * 512);
            ld16(bg + (size_t)(u * 8) * 8192 + kk, bl + u * 512);
        }
        __syncthreads();
#pragma unroll
        for (int ks = 0; ks < 2; ++ks) {
            bf16x8 af[4], bf[4];
#pragma unroll
            for (int rt = 0; rt < 4; ++rt)
                af[rt] = frag(&As[0][0], wr + rt * 16 + fr, ks * 4 + fq);
#pragma unroll
            for (int nt = 0; nt < 4; ++nt)
                bf[nt] = frag(&Bs[0][0], wc + nt * 16 + fr, ks * 4 + fq);
#pragma unroll
            for (int rt = 0; rt < 4; ++rt)
#pragma unroll
                for (int nt = 0; nt < 4; ++nt)
                    acc[rt][nt] = MFMA16(af[rt], bf[nt], acc[rt][nt]);
        }
    }

    __bf16* tp = Ht + (size_t)c * 262144;
#pragma unroll
    for (int rt = 0; rt < 4; ++rt)
#pragma unroll
        for (int nt = 0; nt < 4; ++nt) {
            const int col = n0 + wc + nt * 16 + fr;
#pragma unroll
            for (int r = 0; r < 4; ++r) {
                const int row = m0 + wr + rt * 16 + fq * 4 + r;
                tp[(size_t)row * 512 + col] = (__bf16)acc[rt][nt][r];
            }
        }
}

// ---------------------------------------------------------------------------
// Exclusive prefix over chunk axis: Pt[c] = sum_{c'<c} Ht[c'], fp32 accum,
// bf16 out. Pt[0] never written (t=0 skips inter). 65536 threads, 4 elem each.
// ---------------------------------------------------------------------------
__global__ __launch_bounds__(256) void prefix_scan(
    const __bf16* __restrict__ Ht, __bf16* __restrict__ Pt)
{
    const size_t e = ((size_t)blockIdx.x * 256 + threadIdx.x) * 4;
    float a0 = 0.f, a1 = 0.f, a2 = 0.f, a3 = 0.f;
#pragma unroll 7
    for (int c = 0; c < 63; ++c) {
        bf16x4 h = *(const bf16x4*)(Ht + (size_t)c * 262144 + e);
        a0 += (float)h[0]; a1 += (float)h[1];
        a2 += (float)h[2]; a3 += (float)h[3];
        bf16x4 p;
        p[0] = (__bf16)a0; p[1] = (__bf16)a1;
        p[2] = (__bf16)a2; p[3] = (__bf16)a3;
        *(bf16x4*)(Pt + (size_t)(c + 1) * 262144 + e) = p;
    }
}

// ---------------------------------------------------------------------------
// Out kernel, block (t, n0): out_t = q_t @ Pt_t^T-frag + tril(q_t k_t^T) @ v_t
// Phase A: S = q_t@k_t^T (K=512) -> masked bf16 into padded LDS Ss[128][136]
// Phase B: acc = q_t @ Pt_t (K=512, skipped for t=0)
// Phase C: acc += Ss @ v_t (K=128, A-frags from LDS, B staged from vT)
// Non-atomic fp32 store (block owns its 128x128 tile).
// ---------------------------------------------------------------------------
__global__ __launch_bounds__(256) void out_gemm(
    const __bf16* __restrict__ q, const __bf16* __restrict__ k,
    const __bf16* __restrict__ vT, const __bf16* __restrict__ Pt,
    float* __restrict__ out)
{
    __shared__ __align__(16) __bf16 As[128][64];
    __shared__ __align__(16) __bf16 Bs[128][64];
    __shared__ __align__(16) __bf16 Ss[128][136]; // +8 pad: 2-way banks on b128

    const int t  = blockIdx.x;
    const int n0 = blockIdx.y * 128;

    const int tid  = threadIdx.x;
    const int wave = tid >> 6, lane = tid & 63;
    const int fr = lane & 15, fq = lane >> 4;
    const int wr = (wave >> 1) * 64, wc = (wave & 1) * 64;
    const int lr = lane >> 3;
    const int cd = (lane & 7) ^ lr;

    f32x4 acc[4][4];
#pragma unroll
    for (int a = 0; a < 4; ++a)
#pragma unroll
        for (int b = 0; b < 4; ++b) acc[a][b] = f32x4{0.f, 0.f, 0.f, 0.f};

    const __bf16* ag = q + (size_t)(t * 128 + wave * 32 + lr) * 512 + cd * 8;
    const __bf16* bg = k + (size_t)(t * 128 + wave * 32 + lr) * 512 + cd * 8;
    __bf16* al = &As[wave * 32][0];
    __bf16* bl = &Bs[wave * 32][0];

    // ---- Phase A: diagonal S tile, K=512 ----
    for (int kk = 0; kk < 512; kk += 64) {
        __syncthreads();
#pragma unroll
        for (int u = 0; u < 4; ++u) {
            ld16(ag + (size_t)(u * 8) * 512 + kk, al + u * 512);
            ld16(bg + (size_t)(u * 8) * 512 + kk, bl + u * 512);
        }
        __syncthreads();
#pragma unroll
        for (int ks = 0; ks < 2; ++ks) {
            bf16x8 af[4], bf[4];
#pragma unroll
            for (int rt = 0; rt < 4; ++rt)
                af[rt] = frag(&As[0][0], wr + rt * 16 + fr, ks * 4 + fq);
#pragma unroll
            for (int nt = 0; nt < 4; ++nt)
                bf[nt] = frag(&Bs[0][0], wc + nt * 16 + fr, ks * 4 + fq);
#pragma unroll
            for (int rt = 0; rt < 4; ++rt)
#pragma unroll
                for (int nt = 0; nt < 4; ++nt)
                    acc[rt][nt] = MFMA16(af[rt], bf[nt], acc[rt][nt]);
        }
    }

    // masked S -> LDS (strict lower: keep col < row), then re-zero acc
#pragma unroll
    for (int rt = 0; rt < 4; ++rt)
#pragma unroll
        for (int nt = 0; nt < 4; ++nt) {
            const int col = wc + nt * 16 + fr;
#pragma unroll
            for (int r = 0; r < 4; ++r) {
                const int row = wr + rt * 16 + fq * 4 + r;
                float vv = (col < row) ? acc[rt][nt][r] : 0.f;
                Ss[row][col] = (__bf16)vv;
            }
            acc[rt][nt] = f32x4{0.f, 0.f, 0.f, 0.f};
        }

    // ---- Phase B: inter, acc = q_t @ Pt_t, K=512 ----
    if (t > 0) {
        const __bf16* bg2 = Pt + (size_t)t * 262144
                          + (size_t)(n0 + wave * 32 + lr) * 512 + cd * 8;
        for (int kk = 0; kk < 512; kk += 64) {
            __syncthreads();
#pragma unroll
            for (int u = 0; u < 4; ++u) {
                ld16(ag + (size_t)(u * 8) * 512 + kk, al + u * 512);
                ld16(bg2 + (size_t)(u * 8) * 512 + kk, bl + u * 512);
            }
            __syncthreads();
#pragma unroll
            for (int ks = 0; ks < 2; ++ks) {
                bf16x8 af[4], bf[4];
#pragma unroll
                for (int rt = 0; rt < 4; ++rt)
                    af[rt] = frag(&As[0][0], wr + rt * 16 + fr, ks * 4 + fq);
#pragma unroll
                for (int nt = 0; nt < 4; ++nt)
                    bf[nt] = frag(&Bs[0][0], wc + nt * 16 + fr, ks * 4 + fq);
#pragma unroll
                for (int rt = 0; rt < 4; ++rt)
#pragma unroll
                    for (int nt = 0; nt < 4; ++nt)
                        acc[rt][nt] = MFMA16(af[rt], bf[nt], acc[rt][nt]);
            }
        }
    }

    // ---- Phase C: acc += Ss @ v_t, K=128 (A from Ss LDS, B staged) ----
    const __bf16* bg3 = vT + (size_t)(n0 + wave * 32 + lr) * 8192
                      + t * 128 + cd * 8;
    for (int kk = 0; kk < 128; kk += 64) {
        __syncthreads();   // also makes Ss writes visible on first iter
#pragma unroll
        for (int u = 0; u < 4; ++u)
            ld16(bg3 + (size_t)(u * 8) * 8192 + kk, bl + u * 512);
        __syncthreads();
#pragma unroll
        for (int ks = 0; ks < 2; ++ks) {
            bf16x8 af[4], bf[4];
#pragma unroll
            for (int rt = 0; rt < 4; ++rt)
                af[rt] = *(const bf16x8*)(&Ss[wr + rt * 16 + fr]
                                            [kk + ks * 32 + fq * 8]);
#pragma unroll
            for (int nt = 0; nt < 4; ++nt)
                bf[nt] = frag(&Bs[0][0], wc + nt * 16 + fr, ks * 4 + fq);
#pragma unroll
            for (int rt = 0; rt < 4; ++rt)
#pragma unroll
                for (int nt = 0; nt < 4; ++nt)
                    acc[rt][nt] = MFMA16(af[rt], bf[nt], acc[rt][nt]);
        }
    }

    // epilogue: exclusive owner of this 128x128 tile -> plain fp32 store
#pragma unroll
    for (int rt = 0; rt < 4; ++rt)
#pragma unroll
        for (int nt = 0; nt < 4; ++nt) {
            const int col = n0 + wc + nt * 16 + fr;
#pragma unroll
            for (int r = 0; r < 4; ++r) {
                const int row = t * 128 + wr + rt * 16 + fq * 4 + r;
                out[(size_t)row * 512 + col] = acc[rt][nt][r];
            }
        }
}

// ---------------------------------------------------------------------------
extern "C" void kernel_launch(void* const* d_in, const int* in_sizes, int n_in,
                              void* d_out, int out_size, void* d_ws, size_t ws_size,
                              hipStream_t stream) {
    const float* x  = (const float*)d_in[0];
    const float* y  = (const float*)d_in[1];
    const float* Wq = (const float*)d_in[2];
    const float* Wk = (const float*)d_in[3];
    const float* Wv = (const float*)d_in[4];
    float* out = (float*)d_out;

    const size_t QK = (size_t)8192 * 512;       // 4194304
    __bf16* q  = (__bf16*)d_ws;
    __bf16* k  = q + QK;
    __bf16* v  = k + QK;                        // becomes kT after transpose
    __bf16* vT = v + QK;
    __bf16* xb  = vT + QK;                      // 16777216 elems -> Ht
    __bf16* yb  = xb + 16777216;                // 16777216 elems -> Pt
    __bf16* wqb = yb + 16777216;
    __bf16* wkb = wqb + 1048576;
    __bf16* wvb = wkb + 1048576;
    __bf16* kT = v;                             // alias: v dead after transpose
    __bf16* Ht = xb;                            // alias: xb dead after qkv
    __bf16* Pt = yb;                            // alias: yb dead after qkv

    convert_all<<<17920, 256, 0, stream>>>(x, y, Wq, Wk, Wv, xb, yb, wqb, wkb, wvb);
    gemm_qkv_bf16<<<dim3(64, 4, 3), 256, 0, stream>>>(xb, yb, wqb, wkb, wvb, q, k, v);
    transpose_v<<<dim3(128, 8), 256, 0, stream>>>((const ushort*)v, (ushort*)vT);
    transpose_v<<<dim3(128, 8), 256, 0, stream>>>((const ushort*)k, (ushort*)kT);
    h_gemm<<<dim3(16, 63), 256, 0, stream>>>(vT, kT, Ht);
    prefix_scan<<<256, 256, 0, stream>>>(Ht, Pt);
    out_gemm<<<dim3(64, 4), 256, 0, stream>>>(q, k, vT, Pt, out);
}

// Round 2
// 277.973 us; speedup vs baseline: 1.2113x; 1.0019x over previous
//
#include <hip/hip_runtime.h>
#include <hip/hip_bf16.h>

// q = x@Wq^T*scale; k = y@Wk^T; v = y@Wv^T
// out = strict_lower(q@k^T) @ v  -- computed as causal LINEAR attention:
//   out_t = q_t @ P_t + strict_tril(q_t k_t^T) @ v_t,  P_t = sum_{c<t} k_c^T v_c
//
// v7 (from v6 @ 278.5us):
//  * convert_all: wave-contiguous loads (lane stride 16B within each load
//    instruction, was 32B -> 2x cache lines per instr, 2.44 TB/s). Two float4
//    loads + two bf16x4 stores per lane, all perfectly coalesced.
//  * s_diag: diagonal masked S band computed ONCE (was 4x redundantly inside
//    out_gemm phase A). 2MB band aliases dead wqb. out_gemm loses phase A and
//    the 34KB Ss LDS buffer; phase C stages S via the pv_gemm staging pattern.
// ws (bf16 elems): q[4M] k[4M] v[4M](->kT) vT[4M] | xb[16M](->Ht) yb[16M](->Pt)
//   wq(->Sd)/wk/wv[1M x3]. Peak ~105.5 MiB, unchanged.

typedef __bf16 bf16x8 __attribute__((ext_vector_type(8)));
typedef __bf16 bf16x4 __attribute__((ext_vector_type(4)));
typedef float f32x4 __attribute__((ext_vector_type(4)));

#define MFMA16(a, b, c) __builtin_amdgcn_mfma_f32_16x16x32_bf16(a, b, c, 0, 0, 0)

constexpr float SCALE = 0.04419417382415922f; // 1/sqrt(512)

__device__ __forceinline__ void ld16(const void* g, void* l) {
    __builtin_amdgcn_global_load_lds(
        (__attribute__((address_space(1))) void*)g,
        (__attribute__((address_space(3))) void*)l, 16, 0, 0);
}

// read data-chunk c (16B) of row r from a [128][64] bf16 tile stored with
// slot = c ^ (r&7) swizzle. base = &S[0][0].
__device__ __forceinline__ bf16x8 frag(const __bf16* base, int r, int c) {
    return *(const bf16x8*)((const char*)base + r * 128 + ((c ^ (r & 7)) * 16));
}

__device__ inline bf16x4 pack4(float4 a) {
    bf16x4 r;
    r[0] = (__bf16)a.x; r[1] = (__bf16)a.y;
    r[2] = (__bf16)a.z; r[3] = (__bf16)a.w;
    return r;
}

// ---------------------------------------------------------------------------
// fp32 -> bf16 conversion. Wave owns 512 contiguous floats; lane l loads
// float4 s4[l] and s4[64+l] (16B lane stride per instruction), stores two
// contiguous bf16x4. All region sizes are multiples of 512 -> wave-uniform
// branch. 71680 waves = 17920 blocks.
// ---------------------------------------------------------------------------
__global__ __launch_bounds__(256) void convert_all(
    const float* __restrict__ x, const float* __restrict__ y,
    const float* __restrict__ wqf, const float* __restrict__ wkf,
    const float* __restrict__ wvf, __bf16* __restrict__ xb,
    __bf16* __restrict__ yb, __bf16* __restrict__ wqb,
    __bf16* __restrict__ wkb, __bf16* __restrict__ wvb)
{
    const size_t tid = (size_t)blockIdx.x * 256 + threadIdx.x;
    const size_t w = tid >> 6;
    const int lane = (int)(tid & 63);
    size_t f = w * 512;                       // first float of this wave
    const float* src; __bf16* dst;
    if (f < 16777216)      { src = x;   dst = xb;  }
    else if (f < 33554432) { src = y;   dst = yb;  f -= 16777216; }
    else if (f < 34603008) { src = wqf; dst = wqb; f -= 33554432; }
    else if (f < 35651584) { src = wkf; dst = wkb; f -= 34603008; }
    else                   { src = wvf; dst = wvb; f -= 35651584; }
    const float4* s4 = (const float4*)(src + f);
    float4 a = s4[lane];
    float4 b = s4[64 + lane];
    __bf16* d = dst + f;
    *(bf16x4*)(d + lane * 4)       = pack4(a);
    *(bf16x4*)(d + 256 + lane * 4) = pack4(b);
}

// ---------------------------------------------------------------------------
// bf16 GEMM: C[8192,512] = A[8192,2048] @ B[512,2048]^T  (z selects q/k/v).
// z==0 (q) folds SCALE into the epilogue.
// ---------------------------------------------------------------------------
__global__ __launch_bounds__(256, 3) void gemm_qkv_bf16(
    const __bf16* __restrict__ xb, const __bf16* __restrict__ yb,
    const __bf16* __restrict__ wq, const __bf16* __restrict__ wk,
    const __bf16* __restrict__ wv, __bf16* __restrict__ qo,
    __bf16* __restrict__ ko, __bf16* __restrict__ vo)
{
    constexpr int K = 2048, N = 512;
    __shared__ __align__(16) __bf16 As[128][64];
    __shared__ __align__(16) __bf16 Bs[128][64];

    const int z = blockIdx.z;
    const __bf16* A = (z == 0) ? xb : yb;
    const __bf16* B = (z == 0) ? wq : (z == 1) ? wk : wv;
    __bf16* C = (z == 0) ? qo : (z == 1) ? ko : vo;
    const float mul = (z == 0) ? SCALE : 1.0f;

    const int tid  = threadIdx.x;
    const int wave = tid >> 6, lane = tid & 63;
    const int fr = lane & 15, fq = lane >> 4;
    const int m0 = blockIdx.x * 128, n0 = blockIdx.y * 128;
    const int wr = (wave >> 1) * 64, wc = (wave & 1) * 64;
    const int lr = lane >> 3;
    const int cd = (lane & 7) ^ lr;

    f32x4 acc[4][4];
#pragma unroll
    for (int a = 0; a < 4; ++a)
#pragma unroll
        for (int b = 0; b < 4; ++b) acc[a][b] = f32x4{0.f, 0.f, 0.f, 0.f};

    const __bf16* ag = A + (size_t)(m0 + wave * 32 + lr) * K + cd * 8;
    const __bf16* bg = B + (size_t)(n0 + wave * 32 + lr) * K + cd * 8;
    __bf16* al = &As[wave * 32][0];
    __bf16* bl = &Bs[wave * 32][0];

    for (int kk = 0; kk < K; kk += 64) {
        __syncthreads();
#pragma unroll
        for (int u = 0; u < 4; ++u) {
            ld16(ag + (size_t)(u * 8) * K + kk, al + u * 512);
            ld16(bg + (size_t)(u * 8) * K + kk, bl + u * 512);
        }
        __syncthreads();
#pragma unroll
        for (int ks = 0; ks < 2; ++ks) {
            bf16x8 af[4], bf[4];
#pragma unroll
            for (int rt = 0; rt < 4; ++rt)
                af[rt] = frag(&As[0][0], wr + rt * 16 + fr, ks * 4 + fq);
#pragma unroll
            for (int nt = 0; nt < 4; ++nt)
                bf[nt] = frag(&Bs[0][0], wc + nt * 16 + fr, ks * 4 + fq);
#pragma unroll
            for (int rt = 0; rt < 4; ++rt)
#pragma unroll
                for (int nt = 0; nt < 4; ++nt)
                    acc[rt][nt] = MFMA16(af[rt], bf[nt], acc[rt][nt]);
        }
    }

#pragma unroll
    for (int rt = 0; rt < 4; ++rt)
#pragma unroll
        for (int nt = 0; nt < 4; ++nt) {
            const int col = n0 + wc + nt * 16 + fr;
#pragma unroll
            for (int r = 0; r < 4; ++r) {
                const int row = m0 + wr + rt * 16 + fq * 4 + r;
                C[(size_t)row * N + col] = (__bf16)(acc[rt][nt][r] * mul);
            }
        }
}

// ---------------------------------------------------------------------------
// Transpose [8192,512] -> [512,8192] (bf16), 64x64 LDS tiles. Used for v, k.
// ---------------------------------------------------------------------------
__global__ __launch_bounds__(256) void transpose_v(
    const ushort* __restrict__ v, ushort* __restrict__ vT)
{
    __shared__ ushort tile[64][72];
    const int t = threadIdx.x;
    const int r0 = blockIdx.x * 64;
    const int c0 = blockIdx.y * 64;
    const int lr = t >> 2;
    const int lc = (t & 3) * 16;

    union { float4 f[2]; ushort s[16]; } u;
    const float4* vp = (const float4*)(v + (size_t)(r0 + lr) * 512 + c0 + lc);
    u.f[0] = vp[0];
    u.f[1] = vp[1];
#pragma unroll
    for (int e = 0; e < 16; ++e) tile[lc + e][lr] = u.s[e];
    __syncthreads();
    float4* op = (float4*)(vT + (size_t)(c0 + lr) * 8192 + r0 + lc);
    op[0] = *(const float4*)&tile[lr][lc];
    op[1] = *(const float4*)&tile[lr][lc + 8];
}

// ---------------------------------------------------------------------------
// H kernel: Ht[c][n][d] = sum_{r in chunk c} v[cB+r][n] * k[cB+r][d]
// = (vT_c @ kT_c^T), chunk B=128 rows. grid (16 tiles, 63 chunks), K=128.
// ---------------------------------------------------------------------------
__global__ __launch_bounds__(256, 3) void h_gemm(
    const __bf16* __restrict__ vT, const __bf16* __restrict__ kT,
    __bf16* __restrict__ Ht)
{
    __shared__ __align__(16) __bf16 As[128][64];
    __shared__ __align__(16) __bf16 Bs[128][64];

    const int c  = blockIdx.y;              // chunk 0..62 (Ht[63] never read)
    const int m0 = (blockIdx.x & 3) * 128;  // n (v feature)
    const int n0 = (blockIdx.x >> 2) * 128; // d (k feature)

    const int tid  = threadIdx.x;
    const int wave = tid >> 6, lane = tid & 63;
    const int fr = lane & 15, fq = lane >> 4;
    const int wr = (wave >> 1) * 64, wc = (wave & 1) * 64;
    const int lr = lane >> 3;
    const int cd = (lane & 7) ^ lr;

    f32x4 acc[4][4];
#pragma unroll
    for (int a = 0; a < 4; ++a)
#pragma unroll
        for (int b = 0; b < 4; ++b) acc[a][b] = f32x4{0.f, 0.f, 0.f, 0.f};

    const __bf16* ag = vT + (size_t)(m0 + wave * 32 + lr) * 8192 + c * 128 + cd * 8;
    const __bf16* bg = kT + (size_t)(n0 + wave * 32 + lr) * 8192 + c * 128 + cd * 8;
    __bf16* al = &As[wave * 32][0];
    __bf16* bl = &Bs[wave * 32][0];

    for (int kk = 0; kk < 128; kk += 64) {
        __syncthreads();
#pragma unroll
        for (int u = 0; u < 4; ++u) {
            ld16(ag + (size_t)(u * 8) * 8192 + kk, al + u * 512);
            ld16(bg + (size_t)(u * 8) * 8192 + kk, bl + u * 512);
        }
        __syncthreads();
#pragma unroll
        for (int ks = 0; ks < 2; ++ks) {
            bf16x8 af[4], bf[4];
#pragma unroll
            for (int rt = 0; rt < 4; ++rt)
                af[rt] = frag(&As[0][0], wr + rt * 16 + fr, ks * 4 + fq);
#pragma unroll
            for (int nt = 0; nt < 4; ++nt)
                bf[nt] = frag(&Bs[0][0], wc + nt * 16 + fr, ks * 4 + fq);
#pragma unroll
            for (int rt = 0; rt < 4; ++rt)
#pragma unroll
                for (int nt = 0; nt < 4; ++nt)
                    acc[rt][nt] = MFMA16(af[rt], bf[nt], acc[rt][nt]);
        }
    }

    __bf16* tp = Ht + (size_t)c * 262144;
#pragma unroll
    for (int rt = 0; rt < 4; ++rt)
#pragma unroll
        for (int nt = 0; nt < 4; ++nt) {
            const int col = n0 + wc + nt * 16 + fr;
#pragma unroll
            for (int r = 0; r < 4; ++r) {
                const int row = m0 + wr + rt * 16 + fq * 4 + r;
                tp[(size_t)row * 512 + col] = (__bf16)acc[rt][nt][r];
            }
        }
}

// ---------------------------------------------------------------------------
// Exclusive prefix over chunk axis: Pt[c] = sum_{c'<c} Ht[c'], fp32 accum,
// bf16 out. Pt[0] never written (t=0 skips inter). 65536 threads, 4 elem each.
// ---------------------------------------------------------------------------
__global__ __launch_bounds__(256) void prefix_scan(
    const __bf16* __restrict__ Ht, __bf16* __restrict__ Pt)
{
    const size_t e = ((size_t)blockIdx.x * 256 + threadIdx.x) * 4;
    float a0 = 0.f, a1 = 0.f, a2 = 0.f, a3 = 0.f;
#pragma unroll 7
    for (int c = 0; c < 63; ++c) {
        bf16x4 h = *(const bf16x4*)(Ht + (size_t)c * 262144 + e);
        a0 += (float)h[0]; a1 += (float)h[1];
        a2 += (float)h[2]; a3 += (float)h[3];
        bf16x4 p;
        p[0] = (__bf16)a0; p[1] = (__bf16)a1;
        p[2] = (__bf16)a2; p[3] = (__bf16)a3;
        *(bf16x4*)(Pt + (size_t)(c + 1) * 262144 + e) = p;
    }
}

// ---------------------------------------------------------------------------
// Diagonal S band: Sd[t] = strict_tril(q_t @ k_t^T), bf16 [128][128] row-major
// at Sd + t*16384. 64 blocks, K=512, m97 staging. Computed ONCE (was 4x in
// out_gemm). SCALE already folded into q.
// ---------------------------------------------------------------------------
__global__ __launch_bounds__(256, 3) void s_diag(
    const __bf16* __restrict__ q, const __bf16* __restrict__ k,
    __bf16* __restrict__ Sd)
{
    constexpr int K = 512;
    __shared__ __align__(16) __bf16 As[128][64];
    __shared__ __align__(16) __bf16 Bs[128][64];

    const int t = blockIdx.x;

    const int tid  = threadIdx.x;
    const int wave = tid >> 6, lane = tid & 63;
    const int fr = lane & 15, fq = lane >> 4;
    const int wr = (wave >> 1) * 64, wc = (wave & 1) * 64;
    const int lr = lane >> 3;
    const int cd = (lane & 7) ^ lr;

    f32x4 acc[4][4];
#pragma unroll
    for (int a = 0; a < 4; ++a)
#pragma unroll
        for (int b = 0; b < 4; ++b) acc[a][b] = f32x4{0.f, 0.f, 0.f, 0.f};

    const __bf16* ag = q + (size_t)(t * 128 + wave * 32 + lr) * K + cd * 8;
    const __bf16* bg = k + (size_t)(t * 128 + wave * 32 + lr) * K + cd * 8;
    __bf16* al = &As[wave * 32][0];
    __bf16* bl = &Bs[wave * 32][0];

    for (int kk = 0; kk < K; kk += 64) {
        __syncthreads();
#pragma unroll
        for (int u = 0; u < 4; ++u) {
            ld16(ag + (size_t)(u * 8) * K + kk, al + u * 512);
            ld16(bg + (size_t)(u * 8) * K + kk, bl + u * 512);
        }
        __syncthreads();
#pragma unroll
        for (int ks = 0; ks < 2; ++ks) {
            bf16x8 af[4], bf[4];
#pragma unroll
            for (int rt = 0; rt < 4; ++rt)
                af[rt] = frag(&As[0][0], wr + rt * 16 + fr, ks * 4 + fq);
#pragma unroll
            for (int nt = 0; nt < 4; ++nt)
                bf[nt] = frag(&Bs[0][0], wc + nt * 16 + fr, ks * 4 + fq);
#pragma unroll
            for (int rt = 0; rt < 4; ++rt)
#pragma unroll
                for (int nt = 0; nt < 4; ++nt)
                    acc[rt][nt] = MFMA16(af[rt], bf[nt], acc[rt][nt]);
        }
    }

    __bf16* tp = Sd + (size_t)t * 16384;
#pragma unroll
    for (int rt = 0; rt < 4; ++rt)
#pragma unroll
        for (int nt = 0; nt < 4; ++nt) {
            const int col = wc + nt * 16 + fr;
#pragma unroll
            for (int r = 0; r < 4; ++r) {
                const int row = wr + rt * 16 + fq * 4 + r;
                float vv = (col < row) ? acc[rt][nt][r] : 0.f;
                tp[row * 128 + col] = (__bf16)vv;
            }
        }
}

// ---------------------------------------------------------------------------
// Out kernel, block (t, n0):
// Phase B: acc = q_t @ Pt_t (K=512, skipped for t=0)
// Phase C: acc += Sd[t] @ v_t (K=128, both operands staged via ld16)
// Non-atomic fp32 store (block owns its 128x128 tile).
// ---------------------------------------------------------------------------
__global__ __launch_bounds__(256, 3) void out_gemm(
    const __bf16* __restrict__ q, const __bf16* __restrict__ Sd,
    const __bf16* __restrict__ vT, const __bf16* __restrict__ Pt,
    float* __restrict__ out)
{
    __shared__ __align__(16) __bf16 As[128][64];
    __shared__ __align__(16) __bf16 Bs[128][64];

    const int t  = blockIdx.x;
    const int n0 = blockIdx.y * 128;

    const int tid  = threadIdx.x;
    const int wave = tid >> 6, lane = tid & 63;
    const int fr = lane & 15, fq = lane >> 4;
    const int wr = (wave >> 1) * 64, wc = (wave & 1) * 64;
    const int lr = lane >> 3;
    const int cd = (lane & 7) ^ lr;
    const int srow = wave * 32 + lr;

    f32x4 acc[4][4];
#pragma unroll
    for (int a = 0; a < 4; ++a)
#pragma unroll
        for (int b = 0; b < 4; ++b) acc[a][b] = f32x4{0.f, 0.f, 0.f, 0.f};

    __bf16* al = &As[wave * 32][0];
    __bf16* bl = &Bs[wave * 32][0];

    // ---- Phase B: inter, acc = q_t @ Pt_t, K=512 ----
    if (t > 0) {
        const __bf16* ag = q + (size_t)(t * 128 + srow) * 512 + cd * 8;
        const __bf16* bg2 = Pt + (size_t)t * 262144
                          + (size_t)(n0 + srow) * 512 + cd * 8;
        for (int kk = 0; kk < 512; kk += 64) {
            __syncthreads();
#pragma unroll
            for (int u = 0; u < 4; ++u) {
                ld16(ag + (size_t)(u * 8) * 512 + kk, al + u * 512);
                ld16(bg2 + (size_t)(u * 8) * 512 + kk, bl + u * 512);
            }
            __syncthreads();
#pragma unroll
            for (int ks = 0; ks < 2; ++ks) {
                bf16x8 af[4], bf[4];
#pragma unroll
                for (int rt = 0; rt < 4; ++rt)
                    af[rt] = frag(&As[0][0], wr + rt * 16 + fr, ks * 4 + fq);
#pragma unroll
                for (int nt = 0; nt < 4; ++nt)
                    bf[nt] = frag(&Bs[0][0], wc + nt * 16 + fr, ks * 4 + fq);
#pragma unroll
                for (int rt = 0; rt < 4; ++rt)
#pragma unroll
                    for (int nt = 0; nt < 4; ++nt)
                        acc[rt][nt] = MFMA16(af[rt], bf[nt], acc[rt][nt]);
            }
        }
    }

    // ---- Phase C: acc += Sd[t] @ v_t, K=128 (both staged via ld16) ----
    const __bf16* at3 = Sd + (size_t)t * 16384 + (size_t)srow * 128 + cd * 8;
    const __bf16* bg3 = vT + (size_t)(n0 + srow) * 8192 + t * 128 + cd * 8;
    for (int kk = 0; kk < 128; kk += 64) {
        __syncthreads();
#pragma unroll
        for (int u = 0; u < 4; ++u) {
            ld16(at3 + (size_t)(u * 8) * 128 + kk, al + u * 512);
            ld16(bg3 + (size_t)(u * 8) * 8192 + kk, bl + u * 512);
        }
        __syncthreads();
#pragma unroll
        for (int ks = 0; ks < 2; ++ks) {
            bf16x8 af[4], bf[4];
#pragma unroll
            for (int rt = 0; rt < 4; ++rt)
                af[rt] = frag(&As[0][0], wr + rt * 16 + fr, ks * 4 + fq);
#pragma unroll
            for (int nt = 0; nt < 4; ++nt)
                bf[nt] = frag(&Bs[0][0], wc + nt * 16 + fr, ks * 4 + fq);
#pragma unroll
            for (int rt = 0; rt < 4; ++rt)
#pragma unroll
                for (int nt = 0; nt < 4; ++nt)
                    acc[rt][nt] = MFMA16(af[rt], bf[nt], acc[rt][nt]);
        }
    }

    // epilogue: exclusive owner of this 128x128 tile -> plain fp32 store
#pragma unroll
    for (int rt = 0; rt < 4; ++rt)
#pragma unroll
        for (int nt = 0; nt < 4; ++nt) {
            const int col = n0 + wc + nt * 16 + fr;
#pragma unroll
            for (int r = 0; r < 4; ++r) {
                const int row = t * 128 + wr + rt * 16 + fq * 4 + r;
                out[(size_t)row * 512 + col] = acc[rt][nt][r];
            }
        }
}

// ---------------------------------------------------------------------------
extern "C" void kernel_launch(void* const* d_in, const int* in_sizes, int n_in,
                              void* d_out, int out_size, void* d_ws, size_t ws_size,
                              hipStream_t stream) {
    const float* x  = (const float*)d_in[0];
    const float* y  = (const float*)d_in[1];
    const float* Wq = (const float*)d_in[2];
    const float* Wk = (const float*)d_in[3];
    const float* Wv = (const float*)d_in[4];
    float* out = (float*)d_out;

    const size_t QK = (size_t)8192 * 512;       // 4194304
    __bf16* q  = (__bf16*)d_ws;
    __bf16* k  = q + QK;
    __bf16* v  = k + QK;                        // becomes kT after transpose
    __bf16* vT = v + QK;
    __bf16* xb  = vT + QK;                      // 16777216 elems -> Ht
    __bf16* yb  = xb + 16777216;                // 16777216 elems -> Pt
    __bf16* wqb = yb + 16777216;
    __bf16* wkb = wqb + 1048576;
    __bf16* wvb = wkb + 1048576;
    __bf16* kT = v;                             // alias: v dead after transpose
    __bf16* Ht = xb;                            // alias: xb dead after qkv
    __bf16* Pt = yb;                            // alias: yb dead after qkv
    __bf16* Sd = wqb;                           // alias: wqb dead after qkv

    convert_all<<<17920, 256, 0, stream>>>(x, y, Wq, Wk, Wv, xb, yb, wqb, wkb, wvb);
    gemm_qkv_bf16<<<dim3(64, 4, 3), 256, 0, stream>>>(xb, yb, wqb, wkb, wvb, q, k, v);
    transpose_v<<<dim3(128, 8), 256, 0, stream>>>((const ushort*)v, (ushort*)vT);
    transpose_v<<<dim3(128, 8), 256, 0, stream>>>((const ushort*)k, (ushort*)kT);
    h_gemm<<<dim3(16, 63), 256, 0, stream>>>(vT, kT, Ht);
    s_diag<<<64, 256, 0, stream>>>(q, k, Sd);
    prefix_scan<<<256, 256, 0, stream>>>(Ht, Pt);
    out_gemm<<<dim3(64, 4), 256, 0, stream>>>(q, Sd, vT, Pt, out);
}